// Round 9
// baseline (204.875 us; speedup 1.0000x reference)
//
#include <hip/hip_runtime.h>
#include <hip/hip_bf16.h>

#define HDIM 1024
#define IDIM 768
#define NE   8

typedef __attribute__((ext_vector_type(8))) __bf16 bf16x8;
typedef __attribute__((ext_vector_type(4))) __bf16 bf16x4;
typedef __attribute__((ext_vector_type(4))) float  f32x4;

__device__ __forceinline__ void gload16(const void* g, void* l) {
    __builtin_amdgcn_global_load_lds(
        (const __attribute__((address_space(1))) void*)g,
        (__attribute__((address_space(3))) void*)l, 16, 0, 0);
}

// swizzled element offset within one [64 rows][64 k] bf16 tile:
// row r, 16B-chunk q (q = j*4 + fc) -> slot q ^ (r&7)
__device__ __forceinline__ int swzoff(int r, int j, int fc) {
    return r * 64 + ((((j << 2) + fc) ^ (r & 7)) << 3);
}

// ---------------- Router ----------------
__global__ __launch_bounds__(256) void router_kernel(
    const float* __restrict__ x, const float* __restrict__ gate_w,
    int* __restrict__ counts, int* __restrict__ tok_list,
    int* __restrict__ sel_e, int* __restrict__ sel_pos, float* __restrict__ sel_w,
    int T)
{
    int wave = (blockIdx.x * blockDim.x + threadIdx.x) >> 6;
    int lane = threadIdx.x & 63;
    if (wave >= T) return;
    const float* xr = x + (size_t)wave * HDIM;

    float acc[NE];
    #pragma unroll
    for (int e = 0; e < NE; ++e) acc[e] = 0.f;

    for (int h = lane; h < HDIM; h += 64) {
        float xv = xr[h];
        const float* g = gate_w + (size_t)h * NE;
        #pragma unroll
        for (int e = 0; e < NE; ++e) acc[e] += xv * g[e];
    }
    #pragma unroll
    for (int e = 0; e < NE; ++e) {
        float v = acc[e];
        #pragma unroll
        for (int s = 32; s > 0; s >>= 1) v += __shfl_xor(v, s);
        acc[e] = v;
    }
    if (lane == 0) {
        int e0 = 0;
        #pragma unroll
        for (int e = 1; e < NE; ++e) if (acc[e] > acc[e0]) e0 = e;
        int e1 = -1;
        #pragma unroll
        for (int e = 0; e < NE; ++e) {
            if (e == e0) continue;
            if (e1 < 0 || acc[e] > acc[e1]) e1 = e;
        }
        float d  = __expf(acc[e1] - acc[e0]);
        float w0 = 1.f / (1.f + d);
        float w1 = 1.f - w0;
        int p0 = atomicAdd(&counts[e0], 1);
        tok_list[e0 * T + p0] = wave;
        int p1 = atomicAdd(&counts[e1], 1);
        tok_list[e1 * T + p1] = wave;
        sel_e[wave * 2 + 0] = e0;  sel_pos[wave * 2 + 0] = p0;  sel_w[wave * 2 + 0] = w0;
        sel_e[wave * 2 + 1] = e1;  sel_pos[wave * 2 + 1] = p1;  sel_w[wave * 2 + 1] = w1;
    }
}

__global__ void prefix_kernel(const int* __restrict__ counts, int* __restrict__ offsets)
{
    if (threadIdx.x == 0 && blockIdx.x == 0) {
        int s = 0;
        for (int e = 0; e < NE; ++e) { offsets[e] = s; s += counts[e]; }
    }
}

// ---------------- Gather x rows into sorted-slot order, fp32 -> bf16 ----------------
__global__ __launch_bounds__(256) void gather_x_kernel(
    const float* __restrict__ x, const int* __restrict__ offsets,
    const int* __restrict__ tok_list, __bf16* __restrict__ xg, int T)
{
    int s = (blockIdx.x * blockDim.x + threadIdx.x) >> 6;
    int lane = threadIdx.x & 63;
    if (s >= 2 * T) return;
    int e = 0;
    #pragma unroll
    for (int k = 1; k < NE; ++k) if (s >= offsets[k]) e = k;
    int pos = s - offsets[e];
    int tok = tok_list[e * T + pos];
    const float* xr = x + (size_t)tok * HDIM;
    __bf16* dr = xg + (size_t)s * HDIM;
    for (int j = lane * 4; j < HDIM; j += 256) {
        float4 v = *(const float4*)&xr[j];
        bf16x4 b;
        b[0] = (__bf16)v.x; b[1] = (__bf16)v.y; b[2] = (__bf16)v.z; b[3] = (__bf16)v.w;
        *(bf16x4*)&dr[j] = b;
    }
}

// ---------------- Gate+Up MFMA: fp32 weights reg-staged+cvt, X via gload_lds ------
// grid = nx*12*8; e = bid&7 (expert-per-XCD). Ring-3, 1-deep W reg pipeline.
__global__ __launch_bounds__(256) void gateup_mfma_kernel(
    const __bf16* __restrict__ xg,
    const float* __restrict__ w_gate, const float* __restrict__ w_up,
    const int* __restrict__ counts, const int* __restrict__ offsets,
    __bf16* __restrict__ Abuf, int T, int nx)
{
    int bid = blockIdx.x;
    int e = bid & 7;
    int rem = bid >> 3;
    int x_t = rem % nx, i_t = rem / nx;
    int n = counts[e];
    int t0 = x_t * 64;
    if (t0 >= n) return;
    int i0 = i_t * 64;
    int base = offsets[e];

    __shared__ __bf16 lds[3 * 12288];   // ring3 x {G 4096, U 4096, X 4096} elems = 72 KB

    int tid = threadIdx.x;
    int w = tid >> 6, lane = tid & 63;
    int wr = w >> 1, wc = w & 1;

    const float* gWf = w_gate + (size_t)e * HDIM * IDIM;   // [H][I] natural
    const float* uWf = w_up   + (size_t)e * HDIM * IDIM;
    const __bf16* xS = xg + (size_t)(base + t0) * HDIM;

    // X staging (gload_lds, pre-swizzled source chunks)
    int sr0 = w * 16 + (lane >> 3);
    int sr1 = sr0 + 8;
    int sc0 = ((lane & 7) ^ (sr0 & 7)) * 8;
    int sc1 = ((lane & 7) ^ (sr1 & 7)) * 8;
    const __bf16* xp0 = xS + (size_t)sr0 * HDIM + sc0;
    const __bf16* xp1 = xS + (size_t)sr1 * HDIM + sc1;
    int dbase = w * 1024;

    // W reg-staging: lane = tile row r (i-dim), wave w covers h-groups (w+4j)*4
    const float* gcol = gWf + i0 + lane;
    const float* ucol = uWf + i0 + lane;
    int wofs[4];
    #pragma unroll
    for (int j = 0; j < 4; ++j) {
        int h0 = (w + j * 4) * 4;
        wofs[j] = lane * 64 + ((((h0 >> 3) ^ (lane & 7)) << 3) | (h0 & 7));
    }

    float rg[4][4], ru[4][4];

#define WLOAD_GU(kt) { \
    int k0 = (kt) * 64; \
    _Pragma("unroll") \
    for (int j = 0; j < 4; ++j) { \
        int h0 = (w + j * 4) * 4; \
        const float* gp = gcol + (size_t)(k0 + h0) * IDIM; \
        const float* up = ucol + (size_t)(k0 + h0) * IDIM; \
        _Pragma("unroll") \
        for (int d = 0; d < 4; ++d) { \
            rg[j][d] = gp[(size_t)d * IDIM]; \
            ru[j][d] = up[(size_t)d * IDIM]; \
        } \
    } \
}
#define WWRITE_GU(buf) { \
    __bf16* L = lds + (buf) * 12288; \
    _Pragma("unroll") \
    for (int j = 0; j < 4; ++j) { \
        bf16x4 gb, ub; \
        _Pragma("unroll") \
        for (int d = 0; d < 4; ++d) { gb[d] = (__bf16)rg[j][d]; ub[d] = (__bf16)ru[j][d]; } \
        *(bf16x4*)&L[wofs[j]] = gb; \
        *(bf16x4*)&L[4096 + wofs[j]] = ub; \
    } \
}
#define XLOAD_GU(buf, kt) { \
    int k0 = (kt) * 64; \
    __bf16* L = lds + (buf) * 12288; \
    gload16(xp0 + k0, L + 8192 + dbase); \
    gload16(xp1 + k0, L + 8192 + dbase + 512); \
}

    f32x4 accg[2][2], accu[2][2];
    #pragma unroll
    for (int a = 0; a < 2; ++a)
        #pragma unroll
        for (int b = 0; b < 2; ++b) { accg[a][b] = (f32x4)0.f; accu[a][b] = (f32x4)0.f; }

    int fr = lane & 15, fc = lane >> 4;
    int ra0 = wc * 32 + fr,  ra1 = ra0 + 16;   // weight (i) rows
    int rb0 = wr * 32 + fr,  rb1 = rb0 + 16;   // slot rows
    int oA0[2] = { swzoff(ra0, 0, fc), swzoff(ra0, 1, fc) };
    int oA1[2] = { swzoff(ra1, 0, fc), swzoff(ra1, 1, fc) };
    int oB0[2] = { swzoff(rb0, 0, fc), swzoff(rb0, 1, fc) };
    int oB1[2] = { swzoff(rb1, 0, fc), swzoff(rb1, 1, fc) };

    const int NK = HDIM / 64;   // 16
    // Prologue: W(0) load+write, X(0); then W(1) load (written inside iter 0), X(1).
    WLOAD_GU(0);
    XLOAD_GU(0, 0);
    WWRITE_GU(0);
    WLOAD_GU(1);
    XLOAD_GU(1, 1);

    for (int kt = 0; kt < NK; ++kt) {
        // retire X(kt); keep W(kt+1)[32] + X(kt+1)[2] in flight
        if (kt < NK - 1) asm volatile("s_waitcnt vmcnt(34) lgkmcnt(0)" ::: "memory");
        else             asm volatile("s_waitcnt vmcnt(0) lgkmcnt(0)" ::: "memory");
        __builtin_amdgcn_s_barrier();
        if (kt + 1 < NK) WWRITE_GU((kt + 1) % 3);          // regs from iter kt-1
        if (kt + 2 < NK) { WLOAD_GU(kt + 2); XLOAD_GU((kt + 2) % 3, kt + 2); }

        const __bf16* L  = lds + (kt % 3) * 12288;
        const __bf16* Lg = L;
        const __bf16* Lu = L + 4096;
        const __bf16* Lx = L + 8192;
        __builtin_amdgcn_s_setprio(1);
        #pragma unroll
        for (int j = 0; j < 2; ++j) {
            bf16x8 ag0 = *(const bf16x8*)(Lg + oA0[j]);
            bf16x8 ag1 = *(const bf16x8*)(Lg + oA1[j]);
            bf16x8 au0 = *(const bf16x8*)(Lu + oA0[j]);
            bf16x8 au1 = *(const bf16x8*)(Lu + oA1[j]);
            bf16x8 bx0 = *(const bf16x8*)(Lx + oB0[j]);
            bf16x8 bx1 = *(const bf16x8*)(Lx + oB1[j]);
            accg[0][0] = __builtin_amdgcn_mfma_f32_16x16x32_bf16(ag0, bx0, accg[0][0], 0, 0, 0);
            accg[0][1] = __builtin_amdgcn_mfma_f32_16x16x32_bf16(ag1, bx0, accg[0][1], 0, 0, 0);
            accg[1][0] = __builtin_amdgcn_mfma_f32_16x16x32_bf16(ag0, bx1, accg[1][0], 0, 0, 0);
            accg[1][1] = __builtin_amdgcn_mfma_f32_16x16x32_bf16(ag1, bx1, accg[1][1], 0, 0, 0);
            accu[0][0] = __builtin_amdgcn_mfma_f32_16x16x32_bf16(au0, bx0, accu[0][0], 0, 0, 0);
            accu[0][1] = __builtin_amdgcn_mfma_f32_16x16x32_bf16(au1, bx0, accu[0][1], 0, 0, 0);
            accu[1][0] = __builtin_amdgcn_mfma_f32_16x16x32_bf16(au0, bx1, accu[1][0], 0, 0, 0);
            accu[1][1] = __builtin_amdgcn_mfma_f32_16x16x32_bf16(au1, bx1, accu[1][1], 0, 0, 0);
        }
        __builtin_amdgcn_s_setprio(0);
    }
#undef WLOAD_GU
#undef WWRITE_GU
#undef XLOAD_GU

    // D: col = lane&15 = slot, row = (lane>>4)*4+reg = i
    int dr4 = (lane >> 4) * 4;
    #pragma unroll
    for (int ti = 0; ti < 2; ++ti) {
        int tl = wr * 32 + ti * 16 + fr;
        if (t0 + tl < n) {
            size_t slotrow = (size_t)(base + t0 + tl) * IDIM;
            #pragma unroll
            for (int ii = 0; ii < 2; ++ii) {
                f32x4 g = accg[ti][ii], u = accu[ti][ii];
                bf16x4 o;
                #pragma unroll
                for (int r = 0; r < 4; ++r) {
                    float gv = g[r];
                    float s = gv / (1.f + __expf(-gv));
                    o[r] = (__bf16)(s * u[r]);
                }
                *(bf16x4*)&Abuf[slotrow + i0 + wc * 32 + ii * 16 + dr4] = o;
            }
        }
    }
}

// ---------------- Down MFMA: fp32 w_down reg-staged+cvt; Y[slot][h] fp32 ----------------
// grid = nx*16*8; e = bid&7.
__global__ __launch_bounds__(256) void down_mfma_kernel(
    const __bf16* __restrict__ Abuf, const float* __restrict__ w_down,
    const int* __restrict__ counts, const int* __restrict__ offsets,
    float* __restrict__ Y, int T, int nx)
{
    int bid = blockIdx.x;
    int e = bid & 7;
    int rem = bid >> 3;
    int x_t = rem % nx, h_t = rem / nx;
    int n = counts[e];
    int t0 = x_t * 64;
    if (t0 >= n) return;
    int hb = h_t * 64;
    int base = offsets[e];

    __shared__ __bf16 lds[3 * 8192];   // ring3 x {W 4096, A 4096} = 48 KB

    int tid = threadIdx.x;
    int w = tid >> 6, lane = tid & 63;
    int wr = w >> 1, wc = w & 1;

    const float* wdf = w_down + (size_t)e * IDIM * HDIM;   // [I][H] natural
    const __bf16* aS = Abuf + (size_t)(base + t0) * IDIM;

    // A staging (gload_lds)
    int sr0 = w * 16 + (lane >> 3);
    int sr1 = sr0 + 8;
    int sc0 = ((lane & 7) ^ (sr0 & 7)) * 8;
    int sc1 = ((lane & 7) ^ (sr1 & 7)) * 8;
    const __bf16* ap0 = aS + (size_t)sr0 * IDIM + sc0;
    const __bf16* ap1 = aS + (size_t)sr1 * IDIM + sc1;
    int dbase = w * 1024;

    // W reg-staging: lane = tile row r (h-dim), wave covers i-groups (w+4j)*4
    const float* wcol = wdf + hb + lane;
    int wofs[4];
    #pragma unroll
    for (int j = 0; j < 4; ++j) {
        int ic = (w + j * 4) * 4;
        wofs[j] = lane * 64 + ((((ic >> 3) ^ (lane & 7)) << 3) | (ic & 7));
    }

    float rw[4][4];

#define WLOAD_D(kt) { \
    int k0 = (kt) * 64; \
    _Pragma("unroll") \
    for (int j = 0; j < 4; ++j) { \
        int ic = (w + j * 4) * 4; \
        const float* wp = wcol + (size_t)(k0 + ic) * HDIM; \
        _Pragma("unroll") \
        for (int d = 0; d < 4; ++d) rw[j][d] = wp[(size_t)d * HDIM]; \
    } \
}
#define WWRITE_D(buf) { \
    __bf16* L = lds + (buf) * 8192; \
    _Pragma("unroll") \
    for (int j = 0; j < 4; ++j) { \
        bf16x4 wb; \
        _Pragma("unroll") \
        for (int d = 0; d < 4; ++d) wb[d] = (__bf16)rw[j][d]; \
        *(bf16x4*)&L[wofs[j]] = wb; \
    } \
}
#define ALOAD_D(buf, kt) { \
    int k0 = (kt) * 64; \
    __bf16* L = lds + (buf) * 8192; \
    gload16(ap0 + k0, L + 4096 + dbase); \
    gload16(ap1 + k0, L + 4096 + dbase + 512); \
}

    f32x4 acc[2][2];
    #pragma unroll
    for (int a = 0; a < 2; ++a)
        #pragma unroll
        for (int b = 0; b < 2; ++b) acc[a][b] = (f32x4)0.f;

    int fr = lane & 15, fc = lane >> 4;
    int ra0 = wc * 32 + fr,  ra1 = ra0 + 16;   // h rows
    int rb0 = wr * 32 + fr,  rb1 = rb0 + 16;   // slot rows
    int oA0[2] = { swzoff(ra0, 0, fc), swzoff(ra0, 1, fc) };
    int oA1[2] = { swzoff(ra1, 0, fc), swzoff(ra1, 1, fc) };
    int oB0[2] = { swzoff(rb0, 0, fc), swzoff(rb0, 1, fc) };
    int oB1[2] = { swzoff(rb1, 0, fc), swzoff(rb1, 1, fc) };

    const int NK = IDIM / 64;   // 12
    WLOAD_D(0);
    ALOAD_D(0, 0);
    WWRITE_D(0);
    WLOAD_D(1);
    ALOAD_D(1, 1);

    for (int kt = 0; kt < NK; ++kt) {
        // retire A(kt); keep W(kt+1)[16] + A(kt+1)[2]
        if (kt < NK - 1) asm volatile("s_waitcnt vmcnt(18) lgkmcnt(0)" ::: "memory");
        else             asm volatile("s_waitcnt vmcnt(0) lgkmcnt(0)" ::: "memory");
        __builtin_amdgcn_s_barrier();
        if (kt + 1 < NK) WWRITE_D((kt + 1) % 3);
        if (kt + 2 < NK) { WLOAD_D(kt + 2); ALOAD_D((kt + 2) % 3, kt + 2); }

        const __bf16* L  = lds + (kt % 3) * 8192;
        const __bf16* Lw = L;
        const __bf16* La = L + 4096;
        __builtin_amdgcn_s_setprio(1);
        #pragma unroll
        for (int j = 0; j < 2; ++j) {
            bf16x8 aw0 = *(const bf16x8*)(Lw + oA0[j]);
            bf16x8 aw1 = *(const bf16x8*)(Lw + oA1[j]);
            bf16x8 ab0 = *(const bf16x8*)(La + oB0[j]);
            bf16x8 ab1 = *(const bf16x8*)(La + oB1[j]);
            acc[0][0] = __builtin_amdgcn_mfma_f32_16x16x32_bf16(aw0, ab0, acc[0][0], 0, 0, 0);
            acc[0][1] = __builtin_amdgcn_mfma_f32_16x16x32_bf16(aw1, ab0, acc[0][1], 0, 0, 0);
            acc[1][0] = __builtin_amdgcn_mfma_f32_16x16x32_bf16(aw0, ab1, acc[1][0], 0, 0, 0);
            acc[1][1] = __builtin_amdgcn_mfma_f32_16x16x32_bf16(aw1, ab1, acc[1][1], 0, 0, 0);
        }
        __builtin_amdgcn_s_setprio(0);
    }
#undef WLOAD_D
#undef WWRITE_D
#undef ALOAD_D

    int dr4 = (lane >> 4) * 4;
    #pragma unroll
    for (int si = 0; si < 2; ++si) {
        int sl = wr * 32 + si * 16 + fr;
        if (t0 + sl < n) {
            float* yrow = Y + (size_t)(base + t0 + sl) * HDIM + hb;
            #pragma unroll
            for (int hi = 0; hi < 2; ++hi) {
                f32x4 a = acc[si][hi];
                *(f32x4*)&yrow[wc * 32 + hi * 16 + dr4] = a;
            }
        }
    }
}

// ---------------- Combine: out[t] = w0*Y[s0] + w1*Y[s1] ----------------
__global__ __launch_bounds__(256) void combine_kernel(
    const float* __restrict__ Y, const int* __restrict__ offsets,
    const int* __restrict__ sel_e, const int* __restrict__ sel_pos,
    const float* __restrict__ sel_w, float* __restrict__ out)
{
    int t = blockIdx.x;
    int h4 = threadIdx.x * 4;
    int s0 = offsets[sel_e[t * 2 + 0]] + sel_pos[t * 2 + 0];
    int s1 = offsets[sel_e[t * 2 + 1]] + sel_pos[t * 2 + 1];
    float w0 = sel_w[t * 2 + 0], w1 = sel_w[t * 2 + 1];
    float4 a = *(const float4*)&Y[(size_t)s0 * HDIM + h4];
    float4 b = *(const float4*)&Y[(size_t)s1 * HDIM + h4];
    float4 o;
    o.x = w0 * a.x + w1 * b.x;  o.y = w0 * a.y + w1 * b.y;
    o.z = w0 * a.z + w1 * b.z;  o.w = w0 * a.w + w1 * b.w;
    *(float4*)&out[(size_t)t * HDIM + h4] = o;
}

extern "C" void kernel_launch(void* const* d_in, const int* in_sizes, int n_in,
                              void* d_out, int out_size, void* d_ws, size_t ws_size,
                              hipStream_t stream)
{
    const float* x      = (const float*)d_in[0];
    const float* gate_w = (const float*)d_in[1];
    const float* w_gate = (const float*)d_in[2];
    const float* w_up   = (const float*)d_in[3];
    const float* w_down = (const float*)d_in[4];
    float* out = (float*)d_out;

    int T = in_sizes[0] / HDIM;
    int nx = (T + 63) / 64;

    char* ws = (char*)d_ws;
    size_t o = 0;
    int* counts  = (int*)(ws + o); o += 32;
    int* offsets = (int*)(ws + o); o += 32;
    int* tok_list = (int*)(ws + o); o += (size_t)NE * T * 4;
    o = (o + 255) & ~(size_t)255;
    int*   sel_e   = (int*)(ws + o); o += (size_t)2 * T * 4;
    int*   sel_pos = (int*)(ws + o); o += (size_t)2 * T * 4;
    float* sel_w   = (float*)(ws + o); o += (size_t)2 * T * 4;
    o = (o + 255) & ~(size_t)255;
    __bf16* xg = (__bf16*)(ws + o);   o += (size_t)(2 * T + 64) * HDIM * 2;
    o = (o + 255) & ~(size_t)255;
    __bf16* Abuf = (__bf16*)(ws + o); o += (size_t)(2 * T + 64) * IDIM * 2;
    o = (o + 255) & ~(size_t)255;
    float* Y = (float*)(ws + o);      o += (size_t)(2 * T + 64) * HDIM * 4;

    hipMemsetAsync(counts, 0, 32, stream);

    router_kernel<<<(T + 3) / 4, 256, 0, stream>>>(x, gate_w, counts, tok_list,
                                                   sel_e, sel_pos, sel_w, T);
    prefix_kernel<<<1, 64, 0, stream>>>(counts, offsets);
    gather_x_kernel<<<(2 * T + 3) / 4, 256, 0, stream>>>(x, offsets, tok_list, xg, T);

    gateup_mfma_kernel<<<nx * (IDIM / 64) * NE, 256, 0, stream>>>(
        xg, w_gate, w_up, counts, offsets, Abuf, T, nx);

    down_mfma_kernel<<<nx * (HDIM / 64) * NE, 256, 0, stream>>>(
        Abuf, w_down, counts, offsets, Y, T, nx);

    combine_kernel<<<T, 256, 0, stream>>>(Y, offsets, sel_e, sel_pos, sel_w, out);
}

// Round 10
// 186.806 us; speedup vs baseline: 1.0967x; 1.0967x over previous
//
#include <hip/hip_runtime.h>
#include <hip/hip_bf16.h>

#define HDIM 1024
#define IDIM 768
#define NE   8

typedef __attribute__((ext_vector_type(8))) __bf16 bf16x8;
typedef __attribute__((ext_vector_type(4))) __bf16 bf16x4;
typedef __attribute__((ext_vector_type(4))) float  f32x4;

__device__ __forceinline__ void gload16(const void* g, void* l) {
    __builtin_amdgcn_global_load_lds(
        (const __attribute__((address_space(1))) void*)g,
        (__attribute__((address_space(3))) void*)l, 16, 0, 0);
}

// swizzled element offset within one [rows][64 k] bf16 tile:
// row r, 16B-chunk q (q = j*4 + fc) -> slot q ^ (r&7)
__device__ __forceinline__ int swzoff(int r, int j, int fc) {
    return r * 64 + ((((j << 2) + fc) ^ (r & 7)) << 3);
}

// ---------------- Router ----------------
__global__ __launch_bounds__(256) void router_kernel(
    const float* __restrict__ x, const float* __restrict__ gate_w,
    int* __restrict__ counts, int* __restrict__ tok_list,
    int* __restrict__ sel_e, int* __restrict__ sel_pos, float* __restrict__ sel_w,
    int T)
{
    int wave = (blockIdx.x * blockDim.x + threadIdx.x) >> 6;
    int lane = threadIdx.x & 63;
    if (wave >= T) return;
    const float* xr = x + (size_t)wave * HDIM;

    float acc[NE];
    #pragma unroll
    for (int e = 0; e < NE; ++e) acc[e] = 0.f;

    for (int h = lane; h < HDIM; h += 64) {
        float xv = xr[h];
        const float* g = gate_w + (size_t)h * NE;
        #pragma unroll
        for (int e = 0; e < NE; ++e) acc[e] += xv * g[e];
    }
    #pragma unroll
    for (int e = 0; e < NE; ++e) {
        float v = acc[e];
        #pragma unroll
        for (int s = 32; s > 0; s >>= 1) v += __shfl_xor(v, s);
        acc[e] = v;
    }
    if (lane == 0) {
        int e0 = 0;
        #pragma unroll
        for (int e = 1; e < NE; ++e) if (acc[e] > acc[e0]) e0 = e;
        int e1 = -1;
        #pragma unroll
        for (int e = 0; e < NE; ++e) {
            if (e == e0) continue;
            if (e1 < 0 || acc[e] > acc[e1]) e1 = e;
        }
        float d  = __expf(acc[e1] - acc[e0]);
        float w0 = 1.f / (1.f + d);
        float w1 = 1.f - w0;
        int p0 = atomicAdd(&counts[e0], 1);
        tok_list[e0 * T + p0] = wave;
        int p1 = atomicAdd(&counts[e1], 1);
        tok_list[e1 * T + p1] = wave;
        sel_e[wave * 2 + 0] = e0;  sel_pos[wave * 2 + 0] = p0;  sel_w[wave * 2 + 0] = w0;
        sel_e[wave * 2 + 1] = e1;  sel_pos[wave * 2 + 1] = p1;  sel_w[wave * 2 + 1] = w1;
    }
}

__global__ void prefix_kernel(const int* __restrict__ counts, int* __restrict__ offsets)
{
    if (threadIdx.x == 0 && blockIdx.x == 0) {
        int s = 0;
        for (int e = 0; e < NE; ++e) { offsets[e] = s; s += counts[e]; }
    }
}

// ---------------- Gather x rows into sorted-slot order, fp32 -> bf16 ----------------
__global__ __launch_bounds__(256) void gather_x_kernel(
    const float* __restrict__ x, const int* __restrict__ offsets,
    const int* __restrict__ tok_list, __bf16* __restrict__ xg, int T)
{
    int s = (blockIdx.x * blockDim.x + threadIdx.x) >> 6;
    int lane = threadIdx.x & 63;
    if (s >= 2 * T) return;
    int e = 0;
    #pragma unroll
    for (int k = 1; k < NE; ++k) if (s >= offsets[k]) e = k;
    int pos = s - offsets[e];
    int tok = tok_list[e * T + pos];
    const float* xr = x + (size_t)tok * HDIM;
    __bf16* dr = xg + (size_t)s * HDIM;
    for (int j = lane * 4; j < HDIM; j += 256) {
        float4 v = *(const float4*)&xr[j];
        bf16x4 b;
        b[0] = (__bf16)v.x; b[1] = (__bf16)v.y; b[2] = (__bf16)v.z; b[3] = (__bf16)v.w;
        *(bf16x4*)&dr[j] = b;
    }
}

// ---------------- Fused transpose + convert (all 3 weight tensors, one launch) ----------
// src fp32 [R][C] -> dst bf16 [C][R], per expert. z = mat*8 + e.
__global__ __launch_bounds__(256) void transpose3_kernel(
    const float* __restrict__ wg, const float* __restrict__ wu, const float* __restrict__ wd,
    __bf16* __restrict__ WgT, __bf16* __restrict__ WuT, __bf16* __restrict__ WdT)
{
    int z = blockIdx.z;
    int mat = z >> 3, e = z & 7;
    const float* src; __bf16* dst; int R, C;
    if (mat == 0)      { src = wg; dst = WgT; R = HDIM; C = IDIM; }
    else if (mat == 1) { src = wu; dst = WuT; R = HDIM; C = IDIM; }
    else               { src = wd; dst = WdT; R = IDIM; C = HDIM; }
    int c0 = blockIdx.x * 64, r0 = blockIdx.y * 64;
    if (c0 >= C || r0 >= R) return;
    src += (size_t)e * R * C;
    dst += (size_t)e * R * C;

    __shared__ __bf16 Lt[64][72];   // [c][r], padded
    int t = threadIdx.x;
    int rin = t >> 4, c4 = (t & 15) * 4;
    #pragma unroll
    for (int rr = 0; rr < 4; ++rr) {
        int r = rr * 16 + rin;
        float4 v = *(const float4*)&src[(size_t)(r0 + r) * C + c0 + c4];
        Lt[c4 + 0][r] = (__bf16)v.x; Lt[c4 + 1][r] = (__bf16)v.y;
        Lt[c4 + 2][r] = (__bf16)v.z; Lt[c4 + 3][r] = (__bf16)v.w;
    }
    __syncthreads();
    int c = t >> 4, r4 = (t & 15) * 4;
    #pragma unroll
    for (int j = 0; j < 4; ++j) {
        int cc = c + j * 16;
        bf16x4 v = *(bf16x4*)&Lt[cc][r4];
        *(bf16x4*)&dst[(size_t)(c0 + cc) * R + r0 + r4] = v;
    }
}

// ---------------- Gate+Up MFMA: 64 slot x 32 i tiles, BK=64, ring-3 ----------------
// grid = nx*24*8; e = bid&7 (expert-per-XCD), rem = bid>>3, x_t = rem%nx, i_t = rem/nx.
// Smaller i-tile doubles real block count (384->768) for cross-block latency hiding.
__global__ __launch_bounds__(256) void gateup_mfma_kernel(
    const __bf16* __restrict__ xg,
    const __bf16* __restrict__ WgT, const __bf16* __restrict__ WuT,
    const int* __restrict__ counts, const int* __restrict__ offsets,
    __bf16* __restrict__ Abuf, int T, int nx)
{
    int bid = blockIdx.x;
    int e = bid & 7;
    int rem = bid >> 3;
    int x_t = rem % nx, i_t = rem / nx;
    int n = counts[e];
    int t0 = x_t * 64;
    if (t0 >= n) return;
    int i0 = i_t * 32;
    int base = offsets[e];

    __shared__ __bf16 lds[3 * 8192];   // ring3 x {G 2048, U 2048, X 4096} elems = 48 KB

    int tid = threadIdx.x;
    int w = tid >> 6, lane = tid & 63;
    int wr = w >> 1, wc = w & 1;

    const __bf16* gW = WgT + (size_t)e * IDIM * HDIM;
    const __bf16* uW = WuT + (size_t)e * IDIM * HDIM;
    const __bf16* xS = xg + (size_t)(base + t0) * HDIM;

    // W staging: wave w covers rows [w*8, w*8+8); source pre-swizzled (T2 both-sides).
    int srw = w * 8 + (lane >> 3);
    int scw = ((lane & 7) ^ (srw & 7)) * 8;
    const __bf16* gp = gW + (size_t)(i0 + srw) * HDIM + scw;
    const __bf16* up = uW + (size_t)(i0 + srw) * HDIM + scw;
    // X staging: wave w covers rows [w*16, w*16+16)
    int sr0 = w * 16 + (lane >> 3);
    int sr1 = sr0 + 8;
    int sc0 = ((lane & 7) ^ (sr0 & 7)) * 8;
    int sc1 = ((lane & 7) ^ (sr1 & 7)) * 8;
    const __bf16* xp0 = xS + (size_t)sr0 * HDIM + sc0;
    const __bf16* xp1 = xS + (size_t)sr1 * HDIM + sc1;

#define STAGE_GU(buf, kt) { \
    int k0 = (kt) * 64; \
    __bf16* L = lds + (buf) * 8192; \
    gload16(gp + k0, L + w * 512); \
    gload16(up + k0, L + 2048 + w * 512); \
    gload16(xp0 + k0, L + 4096 + w * 1024); \
    gload16(xp1 + k0, L + 4096 + w * 1024 + 512); \
}

    f32x4 accg[2], accu[2];
    accg[0] = (f32x4)0.f; accg[1] = (f32x4)0.f;
    accu[0] = (f32x4)0.f; accu[1] = (f32x4)0.f;

    int fr = lane & 15, fc = lane >> 4;
    int ra = wc * 16 + fr;                   // weight (i) row in [0,32)
    int rb0 = wr * 32 + fr, rb1 = rb0 + 16;  // slot rows
    int oA[2]  = { swzoff(ra, 0, fc),  swzoff(ra, 1, fc) };
    int oB0[2] = { swzoff(rb0, 0, fc), swzoff(rb0, 1, fc) };
    int oB1[2] = { swzoff(rb1, 0, fc), swzoff(rb1, 1, fc) };

    const int NK = HDIM / 64;   // 16
    STAGE_GU(0, 0);
    STAGE_GU(1, 1);

    for (int kt = 0; kt < NK; ++kt) {
        if (kt < NK - 1) asm volatile("s_waitcnt vmcnt(4)" ::: "memory");
        else             asm volatile("s_waitcnt vmcnt(0)" ::: "memory");
        __builtin_amdgcn_s_barrier();
        if (kt + 2 < NK) STAGE_GU((kt + 2) % 3, kt + 2);
        const __bf16* L  = lds + (kt % 3) * 8192;
        const __bf16* Lg = L;
        const __bf16* Lu = L + 2048;
        const __bf16* Lx = L + 4096;
        __builtin_amdgcn_s_setprio(1);
        #pragma unroll
        for (int j = 0; j < 2; ++j) {
            bf16x8 ag  = *(const bf16x8*)(Lg + oA[j]);
            bf16x8 au  = *(const bf16x8*)(Lu + oA[j]);
            bf16x8 bx0 = *(const bf16x8*)(Lx + oB0[j]);
            bf16x8 bx1 = *(const bf16x8*)(Lx + oB1[j]);
            accg[0] = __builtin_amdgcn_mfma_f32_16x16x32_bf16(ag, bx0, accg[0], 0, 0, 0);
            accg[1] = __builtin_amdgcn_mfma_f32_16x16x32_bf16(ag, bx1, accg[1], 0, 0, 0);
            accu[0] = __builtin_amdgcn_mfma_f32_16x16x32_bf16(au, bx0, accu[0], 0, 0, 0);
            accu[1] = __builtin_amdgcn_mfma_f32_16x16x32_bf16(au, bx1, accu[1], 0, 0, 0);
        }
        __builtin_amdgcn_s_setprio(0);
    }
#undef STAGE_GU

    // D: col = lane&15 = slot, row = (lane>>4)*4+reg = i
    int dr4 = (lane >> 4) * 4;
    #pragma unroll
    for (int ti = 0; ti < 2; ++ti) {
        int tl = wr * 32 + ti * 16 + fr;
        if (t0 + tl < n) {
            size_t slotrow = (size_t)(base + t0 + tl) * IDIM;
            f32x4 g = accg[ti], u = accu[ti];
            bf16x4 o;
            #pragma unroll
            for (int r = 0; r < 4; ++r) {
                float gv = g[r];
                float s = gv / (1.f + __expf(-gv));
                o[r] = (__bf16)(s * u[r]);
            }
            *(bf16x4*)&Abuf[slotrow + i0 + wc * 16 + dr4] = o;
        }
    }
}

// ---------------- Down MFMA: BK=64, ring-3, XCD-swizzled; Y[slot][h] fp32 ----------------
// grid = nx*16*8; e = bid&7, rem = bid>>3, x_t = rem%nx, h_t = rem/nx.  (R7-verified)
__global__ __launch_bounds__(256) void down_mfma_kernel(
    const __bf16* __restrict__ Abuf, const __bf16* __restrict__ WdT,
    const int* __restrict__ counts, const int* __restrict__ offsets,
    float* __restrict__ Y, int T, int nx)
{
    int bid = blockIdx.x;
    int e = bid & 7;
    int rem = bid >> 3;
    int x_t = rem % nx, h_t = rem / nx;
    int n = counts[e];
    int t0 = x_t * 64;
    if (t0 >= n) return;
    int h0 = h_t * 64;
    int base = offsets[e];

    __shared__ __bf16 lds[3 * 8192];   // 3 bufs x {W,A} x 8KB = 48 KB

    int tid = threadIdx.x;
    int w = tid >> 6, lane = tid & 63;
    int wr = w >> 1, wc = w & 1;

    const __bf16* dW = WdT + (size_t)e * HDIM * IDIM;   // [H][I]
    const __bf16* aS = Abuf + (size_t)(base + t0) * IDIM;

    int sr0 = w * 16 + (lane >> 3);
    int sr1 = sr0 + 8;
    int sc0 = ((lane & 7) ^ (sr0 & 7)) * 8;
    int sc1 = ((lane & 7) ^ (sr1 & 7)) * 8;
    const __bf16* wp0 = dW + (size_t)(h0 + sr0) * IDIM + sc0;
    const __bf16* wp1 = dW + (size_t)(h0 + sr1) * IDIM + sc1;
    const __bf16* ap0 = aS + (size_t)sr0 * IDIM + sc0;
    const __bf16* ap1 = aS + (size_t)sr1 * IDIM + sc1;
    int dbase = w * 1024;

#define STAGE_D(buf, kt) { \
    int k0 = (kt) * 64; \
    __bf16* L = lds + (buf) * 8192; \
    gload16(wp0 + k0, L + dbase);              \
    gload16(wp1 + k0, L + dbase + 512);        \
    gload16(ap0 + k0, L + 4096 + dbase);       \
    gload16(ap1 + k0, L + 4096 + dbase + 512); \
}

    f32x4 acc[2][2];
    #pragma unroll
    for (int a = 0; a < 2; ++a)
        #pragma unroll
        for (int b = 0; b < 2; ++b) acc[a][b] = (f32x4)0.f;

    int fr = lane & 15, fc = lane >> 4;
    int ra0 = wc * 32 + fr,  ra1 = ra0 + 16;   // h rows
    int rb0 = wr * 32 + fr,  rb1 = rb0 + 16;   // slot rows
    int oA0[2] = { swzoff(ra0, 0, fc), swzoff(ra0, 1, fc) };
    int oA1[2] = { swzoff(ra1, 0, fc), swzoff(ra1, 1, fc) };
    int oB0[2] = { swzoff(rb0, 0, fc), swzoff(rb0, 1, fc) };
    int oB1[2] = { swzoff(rb1, 0, fc), swzoff(rb1, 1, fc) };

    const int NK = IDIM / 64;   // 12
    STAGE_D(0, 0);
    STAGE_D(1, 1);

    for (int kt = 0; kt < NK; ++kt) {
        if (kt < NK - 1) asm volatile("s_waitcnt vmcnt(4)" ::: "memory");
        else             asm volatile("s_waitcnt vmcnt(0)" ::: "memory");
        __builtin_amdgcn_s_barrier();
        if (kt + 2 < NK) STAGE_D((kt + 2) % 3, kt + 2);
        const __bf16* L  = lds + (kt % 3) * 8192;
        const __bf16* Lw = L;
        const __bf16* La = L + 4096;
        __builtin_amdgcn_s_setprio(1);
        #pragma unroll
        for (int j = 0; j < 2; ++j) {
            bf16x8 aw0 = *(const bf16x8*)(Lw + oA0[j]);
            bf16x8 aw1 = *(const bf16x8*)(Lw + oA1[j]);
            bf16x8 ab0 = *(const bf16x8*)(La + oB0[j]);
            bf16x8 ab1 = *(const bf16x8*)(La + oB1[j]);
            acc[0][0] = __builtin_amdgcn_mfma_f32_16x16x32_bf16(aw0, ab0, acc[0][0], 0, 0, 0);
            acc[0][1] = __builtin_amdgcn_mfma_f32_16x16x32_bf16(aw1, ab0, acc[0][1], 0, 0, 0);
            acc[1][0] = __builtin_amdgcn_mfma_f32_16x16x32_bf16(aw0, ab1, acc[1][0], 0, 0, 0);
            acc[1][1] = __builtin_amdgcn_mfma_f32_16x16x32_bf16(aw1, ab1, acc[1][1], 0, 0, 0);
        }
        __builtin_amdgcn_s_setprio(0);
    }
#undef STAGE_D

    int dr4 = (lane >> 4) * 4;
    #pragma unroll
    for (int si = 0; si < 2; ++si) {
        int sl = wr * 32 + si * 16 + fr;
        if (t0 + sl < n) {
            float* yrow = Y + (size_t)(base + t0 + sl) * HDIM + h0;
            #pragma unroll
            for (int hi = 0; hi < 2; ++hi) {
                f32x4 a = acc[si][hi];
                *(f32x4*)&yrow[wc * 32 + hi * 16 + dr4] = a;
            }
        }
    }
}

// ---------------- Combine: out[t] = w0*Y[s0] + w1*Y[s1] ----------------
__global__ __launch_bounds__(256) void combine_kernel(
    const float* __restrict__ Y, const int* __restrict__ offsets,
    const int* __restrict__ sel_e, const int* __restrict__ sel_pos,
    const float* __restrict__ sel_w, float* __restrict__ out)
{
    int t = blockIdx.x;
    int h4 = threadIdx.x * 4;
    int s0 = offsets[sel_e[t * 2 + 0]] + sel_pos[t * 2 + 0];
    int s1 = offsets[sel_e[t * 2 + 1]] + sel_pos[t * 2 + 1];
    float w0 = sel_w[t * 2 + 0], w1 = sel_w[t * 2 + 1];
    float4 a = *(const float4*)&Y[(size_t)s0 * HDIM + h4];
    float4 b = *(const float4*)&Y[(size_t)s1 * HDIM + h4];
    float4 o;
    o.x = w0 * a.x + w1 * b.x;  o.y = w0 * a.y + w1 * b.y;
    o.z = w0 * a.z + w1 * b.z;  o.w = w0 * a.w + w1 * b.w;
    *(float4*)&out[(size_t)t * HDIM + h4] = o;
}

extern "C" void kernel_launch(void* const* d_in, const int* in_sizes, int n_in,
                              void* d_out, int out_size, void* d_ws, size_t ws_size,
                              hipStream_t stream)
{
    const float* x      = (const float*)d_in[0];
    const float* gate_w = (const float*)d_in[1];
    const float* w_gate = (const float*)d_in[2];
    const float* w_up   = (const float*)d_in[3];
    const float* w_down = (const float*)d_in[4];
    float* out = (float*)d_out;

    int T = in_sizes[0] / HDIM;
    int nx = (T + 63) / 64;

    char* ws = (char*)d_ws;
    size_t o = 0;
    int* counts  = (int*)(ws + o); o += 32;
    int* offsets = (int*)(ws + o); o += 32;
    int* tok_list = (int*)(ws + o); o += (size_t)NE * T * 4;
    o = (o + 255) & ~(size_t)255;
    int*   sel_e   = (int*)(ws + o); o += (size_t)2 * T * 4;
    int*   sel_pos = (int*)(ws + o); o += (size_t)2 * T * 4;
    float* sel_w   = (float*)(ws + o); o += (size_t)2 * T * 4;
    o = (o + 255) & ~(size_t)255;
    __bf16* xg = (__bf16*)(ws + o);   o += (size_t)(2 * T + 64) * HDIM * 2;
    o = (o + 255) & ~(size_t)255;
    __bf16* Abuf = (__bf16*)(ws + o); o += (size_t)(2 * T + 64) * IDIM * 2;
    o = (o + 255) & ~(size_t)255;
    float* Y = (float*)(ws + o);      o += (size_t)(2 * T + 64) * HDIM * 4;
    o = (o + 255) & ~(size_t)255;
    __bf16* WgT = (__bf16*)(ws + o);  o += (size_t)NE * IDIM * HDIM * 2;
    __bf16* WuT = (__bf16*)(ws + o);  o += (size_t)NE * IDIM * HDIM * 2;
    __bf16* WdT = (__bf16*)(ws + o);  o += (size_t)NE * HDIM * IDIM * 2;

    hipMemsetAsync(counts, 0, 32, stream);

    router_kernel<<<(T + 3) / 4, 256, 0, stream>>>(x, gate_w, counts, tok_list,
                                                   sel_e, sel_pos, sel_w, T);
    prefix_kernel<<<1, 64, 0, stream>>>(counts, offsets);
    gather_x_kernel<<<(2 * T + 3) / 4, 256, 0, stream>>>(x, offsets, tok_list, xg, T);

    transpose3_kernel<<<dim3(16, 16, 24), 256, 0, stream>>>(w_gate, w_up, w_down,
                                                            WgT, WuT, WdT);

    gateup_mfma_kernel<<<nx * (IDIM / 32) * NE, 256, 0, stream>>>(
        xg, WgT, WuT, counts, offsets, Abuf, T, nx);

    down_mfma_kernel<<<nx * (HDIM / 64) * NE, 256, 0, stream>>>(
        Abuf, WdT, counts, offsets, Y, T, nx);

    combine_kernel<<<T, 256, 0, stream>>>(Y, offsets, sel_e, sel_pos, sel_w, out);
}